// Round 1
// baseline (1378.588 us; speedup 1.0000x reference)
//
#include <hip/hip_runtime.h>

#define N_NODES 50000
#define N_EDGES 800000
#define F_NODE 32
#define F_EDGE 16
#define HID 128
#define DEPTH 4
#define N_GRAPHS 128

// ---------------- CSR build (by dst) ----------------

__global__ void hist_kernel(const int* __restrict__ dst, int* __restrict__ counts) {
  int e = blockIdx.x * blockDim.x + threadIdx.x;
  if (e < N_EDGES) atomicAdd(&counts[dst[e]], 1);
}

__global__ __launch_bounds__(1024) void scan_kernel(const int* __restrict__ counts,
                                                    int* __restrict__ row_ptr,
                                                    int* __restrict__ cursor) {
  __shared__ int sums[1024];
  const int n = N_NODES;
  int t = threadIdx.x;
  const int chunk = (n + 1023) / 1024;  // 49
  int beg = t * chunk;
  int end = beg + chunk;
  if (end > n) end = n;
  int s = 0;
  for (int i = beg; i < end; ++i) s += counts[i];
  sums[t] = s;
  __syncthreads();
  // Hillis-Steele inclusive scan over 1024 partials
  for (int off = 1; off < 1024; off <<= 1) {
    int v = (t >= off) ? sums[t - off] : 0;
    __syncthreads();
    sums[t] += v;
    __syncthreads();
  }
  int run = (t == 0) ? 0 : sums[t - 1];
  for (int i = beg; i < end; ++i) {
    row_ptr[i] = run;
    cursor[i] = run;
    run += counts[i];
  }
  if (t == 1023) row_ptr[n] = sums[1023];
}

__global__ void scatter_kernel(const int* __restrict__ dst, int* __restrict__ cursor,
                               int* __restrict__ edge_list) {
  int e = blockIdx.x * blockDim.x + threadIdx.x;
  if (e < N_EDGES) {
    int pos = atomicAdd(&cursor[dst[e]], 1);
    edge_list[pos] = e;
  }
}

// ---------------- init: h = relu(x @ init_w + init_b); h0 = h ----------------

__global__ __launch_bounds__(128) void init_kernel(const float* __restrict__ x,
                                                   const float* __restrict__ Wi,
                                                   const float* __restrict__ bi,
                                                   float* __restrict__ h,
                                                   float* __restrict__ h0) {
  int node = blockIdx.x;
  int j = threadIdx.x;
  __shared__ float xs[F_NODE];
  if (j < F_NODE) xs[j] = x[node * F_NODE + j];
  __syncthreads();
  float acc = bi[j];
#pragma unroll
  for (int k = 0; k < F_NODE; ++k) acc += xs[k] * Wi[k * HID + j];
  float v = acc > 0.f ? acc : 0.f;
  h[node * HID + j] = v;
  h0[node * HID + j] = v;
}

// ---- aggregation: z[n] = h[n] + sum_{e: dst=n} relu(h[src_e] + edge_attr_e @ We + be) ----

__global__ __launch_bounds__(128) void agg_kernel(const float* __restrict__ h,
                                                  const int* __restrict__ src,
                                                  const float* __restrict__ edge_attr,
                                                  const int* __restrict__ edge_list,
                                                  const int* __restrict__ row_ptr,
                                                  const float* __restrict__ We,
                                                  const float* __restrict__ be,
                                                  float* __restrict__ z) {
  int node = blockIdx.x;
  int j = threadIdx.x;
  __shared__ float Wl[F_EDGE * HID];  // 8 KB
#pragma unroll
  for (int i = 0; i < F_EDGE; ++i) Wl[i * HID + j] = We[i * HID + j];
  float bj = be[j];
  __syncthreads();
  int beg = row_ptr[node], end = row_ptr[node + 1];
  float acc = 0.f;
  for (int i = beg; i < end; ++i) {
    int eid = edge_list[i];
    const float4* ea4 = (const float4*)(edge_attr + (size_t)eid * F_EDGE);
    float4 e0 = ea4[0], e1 = ea4[1], e2 = ea4[2], e3 = ea4[3];
    int s = src[eid];
    float ev = bj;
    ev += e0.x * Wl[0 * HID + j] + e0.y * Wl[1 * HID + j] +
          e0.z * Wl[2 * HID + j] + e0.w * Wl[3 * HID + j];
    ev += e1.x * Wl[4 * HID + j] + e1.y * Wl[5 * HID + j] +
          e1.z * Wl[6 * HID + j] + e1.w * Wl[7 * HID + j];
    ev += e2.x * Wl[8 * HID + j] + e2.y * Wl[9 * HID + j] +
          e2.z * Wl[10 * HID + j] + e2.w * Wl[11 * HID + j];
    ev += e3.x * Wl[12 * HID + j] + e3.y * Wl[13 * HID + j] +
          e3.z * Wl[14 * HID + j] + e3.w * Wl[15 * HID + j];
    float m = h[(size_t)s * HID + j] + ev;
    acc += (m > 0.f) ? m : 0.f;
  }
  z[(size_t)node * HID + j] = h[(size_t)node * HID + j] + acc;
}

// ---- MLP GEMM: C = relu(A @ W + bias [+ res]); A,C are [M,128], W [128,128] ----
// BM=64, BN=128 (full), BK=16, 256 threads, 8x4 register tile per thread.
// NOTE: A and C deliberately NOT __restrict__ — GEMM1 runs in place (each block
// reads only its own 64 rows and writes them only in the epilogue).

__global__ __launch_bounds__(256) void mlp_gemm(const float* A,
                                                const float* __restrict__ W,
                                                const float* __restrict__ bias,
                                                const float* __restrict__ res,
                                                float* C) {
  __shared__ float As[64][17];                    // +1 pad
  __shared__ __align__(16) float Ws[16][128];     // float4-readable
  int tid = threadIdx.x;
  int row0 = blockIdx.x * 64;
  int jt = tid & 31;       // j tile: 4 cols at jt*4
  int mt = tid >> 5;       // m tile: 8 rows at mt*8
  int am = tid >> 2, ak = (tid & 3) * 4;          // A staging: 1 float4/thread
  int wk = tid >> 5, wj = (tid & 31) * 4;         // W staging: 2 float4/thread
  float acc[8][4];
#pragma unroll
  for (int a = 0; a < 8; ++a)
#pragma unroll
    for (int b = 0; b < 4; ++b) acc[a][b] = 0.f;

  for (int k0 = 0; k0 < HID; k0 += 16) {
    int arow = row0 + am;
    float4 av = make_float4(0.f, 0.f, 0.f, 0.f);
    if (arow < N_NODES) av = *(const float4*)(A + (size_t)arow * HID + k0 + ak);
    float4 w0 = *(const float4*)(W + (size_t)(k0 + wk) * HID + wj);
    float4 w1 = *(const float4*)(W + (size_t)(k0 + wk + 8) * HID + wj);
    __syncthreads();
    As[am][ak + 0] = av.x;
    As[am][ak + 1] = av.y;
    As[am][ak + 2] = av.z;
    As[am][ak + 3] = av.w;
    *(float4*)&Ws[wk][wj] = w0;
    *(float4*)&Ws[wk + 8][wj] = w1;
    __syncthreads();
#pragma unroll
    for (int k = 0; k < 16; ++k) {
      float4 wv = *(const float4*)&Ws[k][jt * 4];
#pragma unroll
      for (int mm = 0; mm < 8; ++mm) {
        float a = As[mt * 8 + mm][k];
        acc[mm][0] += a * wv.x;
        acc[mm][1] += a * wv.y;
        acc[mm][2] += a * wv.z;
        acc[mm][3] += a * wv.w;
      }
    }
  }

  float4 bv = *(const float4*)(bias + jt * 4);
#pragma unroll
  for (int mm = 0; mm < 8; ++mm) {
    int row = row0 + mt * 8 + mm;
    if (row < N_NODES) {
      float4 o;
      o.x = acc[mm][0] + bv.x;
      o.y = acc[mm][1] + bv.y;
      o.z = acc[mm][2] + bv.z;
      o.w = acc[mm][3] + bv.w;
      if (res) {
        float4 rv = *(const float4*)(res + (size_t)row * HID + jt * 4);
        o.x += rv.x; o.y += rv.y; o.z += rv.z; o.w += rv.w;
      }
      o.x = o.x > 0.f ? o.x : 0.f;
      o.y = o.y > 0.f ? o.y : 0.f;
      o.z = o.z > 0.f ? o.z : 0.f;
      o.w = o.w > 0.f ? o.w : 0.f;
      *(float4*)(C + (size_t)row * HID + jt * 4) = o;
    }
  }
}

// ---------------- pooling (batch is sorted) ----------------

__global__ __launch_bounds__(128) void pool_kernel(const float* __restrict__ h,
                                                   const int* __restrict__ batch,
                                                   float* __restrict__ pooled) {
  int j = threadIdx.x;
  int n0 = blockIdx.x * 256;
  int nend = n0 + 256;
  if (nend > N_NODES) nend = N_NODES;
  int cur = batch[n0];
  float acc = 0.f;
  for (int n = n0; n < nend; ++n) {
    int b = batch[n];
    if (b != cur) {
      atomicAdd(&pooled[cur * HID + j], acc);
      acc = 0.f;
      cur = b;
    }
    acc += h[(size_t)n * HID + j];
  }
  atomicAdd(&pooled[cur * HID + j], acc);
}

// ---------------- final: out[g] = pooled[g] . ffn_w + ffn_b ----------------

__global__ __launch_bounds__(128) void final_kernel(const float* __restrict__ pooled,
                                                    const float* __restrict__ fw,
                                                    const float* __restrict__ fb,
                                                    float* __restrict__ out) {
  int g = blockIdx.x;
  int j = threadIdx.x;
  float v = pooled[g * HID + j] * fw[j];
#pragma unroll
  for (int off = 32; off > 0; off >>= 1) v += __shfl_down(v, off, 64);
  __shared__ float tmp[2];
  if ((j & 63) == 0) tmp[j >> 6] = v;
  __syncthreads();
  if (j == 0) out[g] = tmp[0] + tmp[1] + fb[0];
}

// ---------------- launch ----------------

extern "C" void kernel_launch(void* const* d_in, const int* in_sizes, int n_in,
                              void* d_out, int out_size, void* d_ws, size_t ws_size,
                              hipStream_t stream) {
  const float* x = (const float*)d_in[0];
  const int* edge_index = (const int*)d_in[1];
  const float* edge_attr = (const float*)d_in[2];
  const int* batch = (const int*)d_in[3];
  const float* init_w = (const float*)d_in[4];
  const float* init_b = (const float*)d_in[5];
  const float* edge_w = (const float*)d_in[6];
  const float* edge_b = (const float*)d_in[7];
  const float* mlp_w1 = (const float*)d_in[8];
  const float* mlp_b1 = (const float*)d_in[9];
  const float* mlp_w2 = (const float*)d_in[10];
  const float* mlp_b2 = (const float*)d_in[11];
  const float* ffn_w = (const float*)d_in[12];
  const float* ffn_b = (const float*)d_in[13];

  const int* srcp = edge_index;
  const int* dstp = edge_index + N_EDGES;

  char* ws = (char*)d_ws;
  auto alloc = [&](size_t bytes) {
    char* p = ws;
    ws += (bytes + 255) & ~(size_t)255;
    return p;
  };
  float* h = (float*)alloc((size_t)N_NODES * HID * 4);
  float* h0 = (float*)alloc((size_t)N_NODES * HID * 4);
  float* z1 = (float*)alloc((size_t)N_NODES * HID * 4);
  int* row_ptr = (int*)alloc((size_t)(N_NODES + 1) * 4);
  int* cursor = (int*)alloc((size_t)N_NODES * 4);
  int* counts = (int*)alloc((size_t)N_NODES * 4);
  int* edge_list = (int*)alloc((size_t)N_EDGES * 4);
  float* pooled = (float*)alloc((size_t)N_GRAPHS * HID * 4);

  hipMemsetAsync(counts, 0, (size_t)N_NODES * 4, stream);
  hipMemsetAsync(pooled, 0, (size_t)N_GRAPHS * HID * 4, stream);

  hist_kernel<<<(N_EDGES + 255) / 256, 256, 0, stream>>>(dstp, counts);
  scan_kernel<<<1, 1024, 0, stream>>>(counts, row_ptr, cursor);
  scatter_kernel<<<(N_EDGES + 255) / 256, 256, 0, stream>>>(dstp, cursor, edge_list);

  init_kernel<<<N_NODES, 128, 0, stream>>>(x, init_w, init_b, h, h0);

  for (int d = 0; d < DEPTH; ++d) {
    agg_kernel<<<N_NODES, 128, 0, stream>>>(h, srcp, edge_attr, edge_list, row_ptr,
                                            edge_w + (size_t)d * F_EDGE * HID,
                                            edge_b + (size_t)d * HID, z1);
    mlp_gemm<<<(N_NODES + 63) / 64, 256, 0, stream>>>(
        z1, mlp_w1 + (size_t)d * HID * HID, mlp_b1 + (size_t)d * HID, nullptr, z1);
    mlp_gemm<<<(N_NODES + 63) / 64, 256, 0, stream>>>(
        z1, mlp_w2 + (size_t)d * HID * HID, mlp_b2 + (size_t)d * HID, h0, h);
  }

  pool_kernel<<<(N_NODES + 255) / 256, 128, 0, stream>>>(h, batch, pooled);
  final_kernel<<<N_GRAPHS, 128, 0, stream>>>(pooled, ffn_w, ffn_b, (float*)d_out);
}

// Round 2
// 1061.814 us; speedup vs baseline: 1.2983x; 1.2983x over previous
//
#include <hip/hip_runtime.h>

#define N_NODES 50000
#define N_EDGES 800000
#define F_NODE 32
#define F_EDGE 16
#define HID 128
#define DEPTH 4
#define N_GRAPHS 128

// ---------------- CSR build (by dst) ----------------

__global__ void hist_kernel(const int* __restrict__ dst, int* __restrict__ counts) {
  int e = blockIdx.x * blockDim.x + threadIdx.x;
  if (e < N_EDGES) atomicAdd(&counts[dst[e]], 1);
}

__global__ __launch_bounds__(1024) void scan_kernel(const int* __restrict__ counts,
                                                    int* __restrict__ row_ptr,
                                                    int* __restrict__ cursor) {
  __shared__ int sums[1024];
  const int n = N_NODES;
  int t = threadIdx.x;
  const int chunk = (n + 1023) / 1024;  // 49
  int beg = t * chunk;
  int end = beg + chunk;
  if (end > n) end = n;
  int s = 0;
  for (int i = beg; i < end; ++i) s += counts[i];
  sums[t] = s;
  __syncthreads();
  // Hillis-Steele inclusive scan over 1024 partials
  for (int off = 1; off < 1024; off <<= 1) {
    int v = (t >= off) ? sums[t - off] : 0;
    __syncthreads();
    sums[t] += v;
    __syncthreads();
  }
  int run = (t == 0) ? 0 : sums[t - 1];
  for (int i = beg; i < end; ++i) {
    row_ptr[i] = run;
    cursor[i] = run;
    run += counts[i];
  }
  if (t == 1023) row_ptr[n] = sums[1023];
}

__global__ void scatter_kernel(const int* __restrict__ dst, int* __restrict__ cursor,
                               int* __restrict__ edge_list) {
  int e = blockIdx.x * blockDim.x + threadIdx.x;
  if (e < N_EDGES) {
    int pos = atomicAdd(&cursor[dst[e]], 1);
    edge_list[pos] = e;
  }
}

// ---- permute: src/edge_attr into dst-sorted order (once per call, reused 4x) ----

__global__ void permute_kernel(const int* __restrict__ src,
                               const float* __restrict__ edge_attr,
                               const int* __restrict__ edge_list,
                               int* __restrict__ src_perm,
                               float* __restrict__ ea_perm) {
  int i = blockIdx.x * blockDim.x + threadIdx.x;
  if (i < N_EDGES) {
    int eid = edge_list[i];
    src_perm[i] = src[eid];
    const float4* in4 = (const float4*)(edge_attr + (size_t)eid * F_EDGE);
    float4* out4 = (float4*)(ea_perm + (size_t)i * F_EDGE);
    float4 a = in4[0], b = in4[1], c = in4[2], d = in4[3];
    out4[0] = a; out4[1] = b; out4[2] = c; out4[3] = d;
  }
}

// ---------------- init: h = relu(x @ init_w + init_b); h0 = h ----------------

__global__ __launch_bounds__(128) void init_kernel(const float* __restrict__ x,
                                                   const float* __restrict__ Wi,
                                                   const float* __restrict__ bi,
                                                   float* __restrict__ h,
                                                   float* __restrict__ h0) {
  int node = blockIdx.x;
  int j = threadIdx.x;
  __shared__ float xs[F_NODE];
  if (j < F_NODE) xs[j] = x[node * F_NODE + j];
  __syncthreads();
  float acc = bi[j];
#pragma unroll
  for (int k = 0; k < F_NODE; ++k) acc += xs[k] * Wi[k * HID + j];
  float v = acc > 0.f ? acc : 0.f;
  h[node * HID + j] = v;
  h0[node * HID + j] = v;
}

// ---- aggregation: z[n] = h[n] + sum_{e: dst=n} relu(h[src_e] + ea_e @ We + be) ----
// Weights for column j live in 16 registers (no LDS in the loop).
// Edge loop unrolled x4: 4 independent h-gathers in flight.

__device__ __forceinline__ float edge_mlp(const float4* __restrict__ ea,
                                          const float w[16], float bj) {
  float4 a0 = ea[0], a1 = ea[1], a2 = ea[2], a3 = ea[3];
  float ev = bj;
  ev += a0.x * w[0] + a0.y * w[1] + a0.z * w[2] + a0.w * w[3];
  ev += a1.x * w[4] + a1.y * w[5] + a1.z * w[6] + a1.w * w[7];
  ev += a2.x * w[8] + a2.y * w[9] + a2.z * w[10] + a2.w * w[11];
  ev += a3.x * w[12] + a3.y * w[13] + a3.z * w[14] + a3.w * w[15];
  return ev;
}

__global__ __launch_bounds__(128) void agg_kernel(const float* __restrict__ h,
                                                  const int* __restrict__ src_perm,
                                                  const float* __restrict__ ea_perm,
                                                  const int* __restrict__ row_ptr,
                                                  const float* __restrict__ We,
                                                  const float* __restrict__ be,
                                                  float* __restrict__ z) {
  int node = blockIdx.x;
  int j = threadIdx.x;
  float w[16];
#pragma unroll
  for (int t = 0; t < F_EDGE; ++t) w[t] = We[t * HID + j];
  float bj = be[j];
  int beg = row_ptr[node], end = row_ptr[node + 1];
  float hn = h[(size_t)node * HID + j];
  float acc = 0.f;
  int i = beg;
  for (; i + 4 <= end; i += 4) {
    int s0 = src_perm[i + 0];
    int s1 = src_perm[i + 1];
    int s2 = src_perm[i + 2];
    int s3 = src_perm[i + 3];
    float hv0 = h[(size_t)s0 * HID + j];
    float hv1 = h[(size_t)s1 * HID + j];
    float hv2 = h[(size_t)s2 * HID + j];
    float hv3 = h[(size_t)s3 * HID + j];
    const float4* ea = (const float4*)(ea_perm + (size_t)i * F_EDGE);
    float ev0 = edge_mlp(ea + 0, w, bj);
    float ev1 = edge_mlp(ea + 4, w, bj);
    float ev2 = edge_mlp(ea + 8, w, bj);
    float ev3 = edge_mlp(ea + 12, w, bj);
    float m0 = hv0 + ev0, m1 = hv1 + ev1, m2 = hv2 + ev2, m3 = hv3 + ev3;
    acc += (m0 > 0.f ? m0 : 0.f) + (m1 > 0.f ? m1 : 0.f) +
           (m2 > 0.f ? m2 : 0.f) + (m3 > 0.f ? m3 : 0.f);
  }
  for (; i < end; ++i) {
    int s = src_perm[i];
    float hv = h[(size_t)s * HID + j];
    const float4* ea = (const float4*)(ea_perm + (size_t)i * F_EDGE);
    float m = hv + edge_mlp(ea, w, bj);
    acc += (m > 0.f ? m : 0.f);
  }
  z[(size_t)node * HID + j] = hn + acc;
}

// ---- MLP GEMM: C = relu(A @ W + bias [+ res]); A,C are [M,128], W [128,128] ----
// BM=64, BN=128 (full), BK=16, 256 threads, 8x4 register tile per thread.
// NOTE: A and C deliberately NOT __restrict__ — GEMM1 runs in place (each block
// reads only its own 64 rows and writes them only in the epilogue).

__global__ __launch_bounds__(256) void mlp_gemm(const float* A,
                                                const float* __restrict__ W,
                                                const float* __restrict__ bias,
                                                const float* __restrict__ res,
                                                float* C) {
  __shared__ float As[64][17];                    // +1 pad
  __shared__ __align__(16) float Ws[16][128];     // float4-readable
  int tid = threadIdx.x;
  int row0 = blockIdx.x * 64;
  int jt = tid & 31;       // j tile: 4 cols at jt*4
  int mt = tid >> 5;       // m tile: 8 rows at mt*8
  int am = tid >> 2, ak = (tid & 3) * 4;          // A staging: 1 float4/thread
  int wk = tid >> 5, wj = (tid & 31) * 4;         // W staging: 2 float4/thread
  float acc[8][4];
#pragma unroll
  for (int a = 0; a < 8; ++a)
#pragma unroll
    for (int b = 0; b < 4; ++b) acc[a][b] = 0.f;

  for (int k0 = 0; k0 < HID; k0 += 16) {
    int arow = row0 + am;
    float4 av = make_float4(0.f, 0.f, 0.f, 0.f);
    if (arow < N_NODES) av = *(const float4*)(A + (size_t)arow * HID + k0 + ak);
    float4 w0 = *(const float4*)(W + (size_t)(k0 + wk) * HID + wj);
    float4 w1 = *(const float4*)(W + (size_t)(k0 + wk + 8) * HID + wj);
    __syncthreads();
    As[am][ak + 0] = av.x;
    As[am][ak + 1] = av.y;
    As[am][ak + 2] = av.z;
    As[am][ak + 3] = av.w;
    *(float4*)&Ws[wk][wj] = w0;
    *(float4*)&Ws[wk + 8][wj] = w1;
    __syncthreads();
#pragma unroll
    for (int k = 0; k < 16; ++k) {
      float4 wv = *(const float4*)&Ws[k][jt * 4];
#pragma unroll
      for (int mm = 0; mm < 8; ++mm) {
        float a = As[mt * 8 + mm][k];
        acc[mm][0] += a * wv.x;
        acc[mm][1] += a * wv.y;
        acc[mm][2] += a * wv.z;
        acc[mm][3] += a * wv.w;
      }
    }
  }

  float4 bv = *(const float4*)(bias + jt * 4);
#pragma unroll
  for (int mm = 0; mm < 8; ++mm) {
    int row = row0 + mt * 8 + mm;
    if (row < N_NODES) {
      float4 o;
      o.x = acc[mm][0] + bv.x;
      o.y = acc[mm][1] + bv.y;
      o.z = acc[mm][2] + bv.z;
      o.w = acc[mm][3] + bv.w;
      if (res) {
        float4 rv = *(const float4*)(res + (size_t)row * HID + jt * 4);
        o.x += rv.x; o.y += rv.y; o.z += rv.z; o.w += rv.w;
      }
      o.x = o.x > 0.f ? o.x : 0.f;
      o.y = o.y > 0.f ? o.y : 0.f;
      o.z = o.z > 0.f ? o.z : 0.f;
      o.w = o.w > 0.f ? o.w : 0.f;
      *(float4*)(C + (size_t)row * HID + jt * 4) = o;
    }
  }
}

// ---------------- pooling (batch is sorted) ----------------

__global__ __launch_bounds__(128) void pool_kernel(const float* __restrict__ h,
                                                   const int* __restrict__ batch,
                                                   float* __restrict__ pooled) {
  int j = threadIdx.x;
  int n0 = blockIdx.x * 256;
  int nend = n0 + 256;
  if (nend > N_NODES) nend = N_NODES;
  int cur = batch[n0];
  float acc = 0.f;
  for (int n = n0; n < nend; ++n) {
    int b = batch[n];
    if (b != cur) {
      atomicAdd(&pooled[cur * HID + j], acc);
      acc = 0.f;
      cur = b;
    }
    acc += h[(size_t)n * HID + j];
  }
  atomicAdd(&pooled[cur * HID + j], acc);
}

// ---------------- final: out[g] = pooled[g] . ffn_w + ffn_b ----------------

__global__ __launch_bounds__(128) void final_kernel(const float* __restrict__ pooled,
                                                    const float* __restrict__ fw,
                                                    const float* __restrict__ fb,
                                                    float* __restrict__ out) {
  int g = blockIdx.x;
  int j = threadIdx.x;
  float v = pooled[g * HID + j] * fw[j];
#pragma unroll
  for (int off = 32; off > 0; off >>= 1) v += __shfl_down(v, off, 64);
  __shared__ float tmp[2];
  if ((j & 63) == 0) tmp[j >> 6] = v;
  __syncthreads();
  if (j == 0) out[g] = tmp[0] + tmp[1] + fb[0];
}

// ---------------- launch ----------------

extern "C" void kernel_launch(void* const* d_in, const int* in_sizes, int n_in,
                              void* d_out, int out_size, void* d_ws, size_t ws_size,
                              hipStream_t stream) {
  const float* x = (const float*)d_in[0];
  const int* edge_index = (const int*)d_in[1];
  const float* edge_attr = (const float*)d_in[2];
  const int* batch = (const int*)d_in[3];
  const float* init_w = (const float*)d_in[4];
  const float* init_b = (const float*)d_in[5];
  const float* edge_w = (const float*)d_in[6];
  const float* edge_b = (const float*)d_in[7];
  const float* mlp_w1 = (const float*)d_in[8];
  const float* mlp_b1 = (const float*)d_in[9];
  const float* mlp_w2 = (const float*)d_in[10];
  const float* mlp_b2 = (const float*)d_in[11];
  const float* ffn_w = (const float*)d_in[12];
  const float* ffn_b = (const float*)d_in[13];

  const int* srcp = edge_index;
  const int* dstp = edge_index + N_EDGES;

  char* ws = (char*)d_ws;
  auto alloc = [&](size_t bytes) {
    char* p = ws;
    ws += (bytes + 255) & ~(size_t)255;
    return p;
  };
  float* h = (float*)alloc((size_t)N_NODES * HID * 4);
  float* h0 = (float*)alloc((size_t)N_NODES * HID * 4);
  float* z1 = (float*)alloc((size_t)N_NODES * HID * 4);
  int* row_ptr = (int*)alloc((size_t)(N_NODES + 1) * 4);
  int* cursor = (int*)alloc((size_t)N_NODES * 4);
  int* counts = (int*)alloc((size_t)N_NODES * 4);
  int* edge_list = (int*)alloc((size_t)N_EDGES * 4);
  int* src_perm = (int*)alloc((size_t)N_EDGES * 4);
  float* ea_perm = (float*)alloc((size_t)N_EDGES * F_EDGE * 4);
  float* pooled = (float*)alloc((size_t)N_GRAPHS * HID * 4);

  hipMemsetAsync(counts, 0, (size_t)N_NODES * 4, stream);
  hipMemsetAsync(pooled, 0, (size_t)N_GRAPHS * HID * 4, stream);

  hist_kernel<<<(N_EDGES + 255) / 256, 256, 0, stream>>>(dstp, counts);
  scan_kernel<<<1, 1024, 0, stream>>>(counts, row_ptr, cursor);
  scatter_kernel<<<(N_EDGES + 255) / 256, 256, 0, stream>>>(dstp, cursor, edge_list);
  permute_kernel<<<(N_EDGES + 255) / 256, 256, 0, stream>>>(srcp, edge_attr, edge_list,
                                                            src_perm, ea_perm);

  init_kernel<<<N_NODES, 128, 0, stream>>>(x, init_w, init_b, h, h0);

  for (int d = 0; d < DEPTH; ++d) {
    agg_kernel<<<N_NODES, 128, 0, stream>>>(h, src_perm, ea_perm, row_ptr,
                                            edge_w + (size_t)d * F_EDGE * HID,
                                            edge_b + (size_t)d * HID, z1);
    mlp_gemm<<<(N_NODES + 63) / 64, 256, 0, stream>>>(
        z1, mlp_w1 + (size_t)d * HID * HID, mlp_b1 + (size_t)d * HID, nullptr, z1);
    mlp_gemm<<<(N_NODES + 63) / 64, 256, 0, stream>>>(
        z1, mlp_w2 + (size_t)d * HID * HID, mlp_b2 + (size_t)d * HID, h0, h);
  }

  pool_kernel<<<(N_NODES + 255) / 256, 128, 0, stream>>>(h, batch, pooled);
  final_kernel<<<N_GRAPHS, 128, 0, stream>>>(pooled, ffn_w, ffn_b, (float*)d_out);
}

// Round 3
// 957.515 us; speedup vs baseline: 1.4398x; 1.1089x over previous
//
#include <hip/hip_runtime.h>

#define N_NODES 50000
#define N_EDGES 800000
#define F_NODE 32
#define F_EDGE 16
#define HID 128
#define DEPTH 4
#define N_GRAPHS 128

#define SCAN_BLOCKS ((N_NODES + 255) / 256)  // 196

// ---------------- CSR build (by dst) ----------------

__global__ void hist_kernel(const int* __restrict__ dst, int* __restrict__ counts) {
  int e = blockIdx.x * blockDim.x + threadIdx.x;
  if (e < N_EDGES) atomicAdd(&counts[dst[e]], 1);
}

__device__ __forceinline__ int wave_incl_scan(int v, int lane) {
#pragma unroll
  for (int off = 1; off < 64; off <<= 1) {
    int u = __shfl_up(v, off, 64);
    if (lane >= off) v += u;
  }
  return v;
}

// phase 1: per-block (256-elem tile) sums
__global__ __launch_bounds__(256) void scan_sum_kernel(const int* __restrict__ counts,
                                                       int* __restrict__ bsums) {
  int i = blockIdx.x * 256 + threadIdx.x;
  int v = (i < N_NODES) ? counts[i] : 0;
  int lane = threadIdx.x & 63, wid = threadIdx.x >> 6;
#pragma unroll
  for (int off = 32; off > 0; off >>= 1) v += __shfl_down(v, off, 64);
  __shared__ int ws[4];
  if (lane == 0) ws[wid] = v;
  __syncthreads();
  if (threadIdx.x == 0) bsums[blockIdx.x] = ws[0] + ws[1] + ws[2] + ws[3];
}

// phase 2: exclusive scan of the 196 block sums (single block), total -> row_ptr[N]
__global__ __launch_bounds__(256) void scan_mid_kernel(const int* __restrict__ bsums,
                                                       int* __restrict__ boff,
                                                       int* __restrict__ row_ptr) {
  int t = threadIdx.x;
  int v = (t < SCAN_BLOCKS) ? bsums[t] : 0;
  int lane = t & 63, wid = t >> 6;
  int s = wave_incl_scan(v, lane);
  __shared__ int wsum[4];
  if (lane == 63) wsum[wid] = s;
  __syncthreads();
  int add = 0;
  for (int w = 0; w < wid; ++w) add += wsum[w];
  s += add;
  if (t < SCAN_BLOCKS) boff[t] = s - v;  // exclusive prefix
  if (t == SCAN_BLOCKS - 1) row_ptr[N_NODES] = s;
}

// phase 3: re-scan tiles, add block offset, write row_ptr + cursor
__global__ __launch_bounds__(256) void scan_write_kernel(const int* __restrict__ counts,
                                                         const int* __restrict__ boff,
                                                         int* __restrict__ row_ptr,
                                                         int* __restrict__ cursor) {
  int i = blockIdx.x * 256 + threadIdx.x;
  int v = (i < N_NODES) ? counts[i] : 0;
  int lane = threadIdx.x & 63, wid = threadIdx.x >> 6;
  int s = wave_incl_scan(v, lane);
  __shared__ int wsum[4];
  if (lane == 63) wsum[wid] = s;
  __syncthreads();
  int add = boff[blockIdx.x];
  for (int w = 0; w < wid; ++w) add += wsum[w];
  int excl = s - v + add;
  if (i < N_NODES) {
    row_ptr[i] = excl;
    cursor[i] = excl;
  }
}

// ---- scatter: directly materialize src/edge_attr in dst-sorted order ----

__global__ void scatter_kernel(const int* __restrict__ src, const int* __restrict__ dst,
                               const float* __restrict__ edge_attr,
                               int* __restrict__ cursor, int* __restrict__ src_perm,
                               float* __restrict__ ea_perm) {
  int e = blockIdx.x * blockDim.x + threadIdx.x;
  if (e < N_EDGES) {
    int pos = atomicAdd(&cursor[dst[e]], 1);
    src_perm[pos] = src[e];
    const float4* in4 = (const float4*)(edge_attr + (size_t)e * F_EDGE);
    float4 a = in4[0], b = in4[1], c = in4[2], d = in4[3];
    float4* out4 = (float4*)(ea_perm + (size_t)pos * F_EDGE);
    out4[0] = a; out4[1] = b; out4[2] = c; out4[3] = d;
  }
}

// ---------------- init: h = relu(x @ init_w + init_b); h0 = h ----------------

__global__ __launch_bounds__(128) void init_kernel(const float* __restrict__ x,
                                                   const float* __restrict__ Wi,
                                                   const float* __restrict__ bi,
                                                   float* __restrict__ h,
                                                   float* __restrict__ h0) {
  int node = blockIdx.x;
  int j = threadIdx.x;
  __shared__ float xs[F_NODE];
  if (j < F_NODE) xs[j] = x[node * F_NODE + j];
  __syncthreads();
  float acc = bi[j];
#pragma unroll
  for (int k = 0; k < F_NODE; ++k) acc += xs[k] * Wi[k * HID + j];
  float v = acc > 0.f ? acc : 0.f;
  h[node * HID + j] = v;
  h0[node * HID + j] = v;
}

// ---- aggregation: z[n] = h[n] + sum_{e: dst=n} relu(h[src_e] + ea_e @ We + be) ----
// Weights in 16 registers; 8 nodes per block (amortizes the weight prologue);
// edge loop unrolled x4 for gather MLP.

#define NODES_PER_BLOCK 8

__device__ __forceinline__ float edge_mlp(const float4* __restrict__ ea,
                                          const float w[16], float bj) {
  float4 a0 = ea[0], a1 = ea[1], a2 = ea[2], a3 = ea[3];
  float ev = bj;
  ev += a0.x * w[0] + a0.y * w[1] + a0.z * w[2] + a0.w * w[3];
  ev += a1.x * w[4] + a1.y * w[5] + a1.z * w[6] + a1.w * w[7];
  ev += a2.x * w[8] + a2.y * w[9] + a2.z * w[10] + a2.w * w[11];
  ev += a3.x * w[12] + a3.y * w[13] + a3.z * w[14] + a3.w * w[15];
  return ev;
}

__global__ __launch_bounds__(128) void agg_kernel(const float* __restrict__ h,
                                                  const int* __restrict__ src_perm,
                                                  const float* __restrict__ ea_perm,
                                                  const int* __restrict__ row_ptr,
                                                  const float* __restrict__ We,
                                                  const float* __restrict__ be,
                                                  float* __restrict__ z) {
  int j = threadIdx.x;
  float w[16];
#pragma unroll
  for (int t = 0; t < F_EDGE; ++t) w[t] = We[t * HID + j];
  float bj = be[j];
  int n0 = blockIdx.x * NODES_PER_BLOCK;
  int n1 = n0 + NODES_PER_BLOCK;
  if (n1 > N_NODES) n1 = N_NODES;
  for (int node = n0; node < n1; ++node) {
    int beg = row_ptr[node], end = row_ptr[node + 1];
    float hn = h[(size_t)node * HID + j];
    float acc = 0.f;
    int i = beg;
    for (; i + 4 <= end; i += 4) {
      int s0 = src_perm[i + 0];
      int s1 = src_perm[i + 1];
      int s2 = src_perm[i + 2];
      int s3 = src_perm[i + 3];
      float hv0 = h[(size_t)s0 * HID + j];
      float hv1 = h[(size_t)s1 * HID + j];
      float hv2 = h[(size_t)s2 * HID + j];
      float hv3 = h[(size_t)s3 * HID + j];
      const float4* ea = (const float4*)(ea_perm + (size_t)i * F_EDGE);
      float ev0 = edge_mlp(ea + 0, w, bj);
      float ev1 = edge_mlp(ea + 4, w, bj);
      float ev2 = edge_mlp(ea + 8, w, bj);
      float ev3 = edge_mlp(ea + 12, w, bj);
      float m0 = hv0 + ev0, m1 = hv1 + ev1, m2 = hv2 + ev2, m3 = hv3 + ev3;
      acc += (m0 > 0.f ? m0 : 0.f) + (m1 > 0.f ? m1 : 0.f) +
             (m2 > 0.f ? m2 : 0.f) + (m3 > 0.f ? m3 : 0.f);
    }
    for (; i < end; ++i) {
      int s = src_perm[i];
      float hv = h[(size_t)s * HID + j];
      const float4* ea = (const float4*)(ea_perm + (size_t)i * F_EDGE);
      float m = hv + edge_mlp(ea, w, bj);
      acc += (m > 0.f ? m : 0.f);
    }
    z[(size_t)node * HID + j] = hn + acc;
  }
}

// ---- MLP GEMM: C = relu(A @ W + bias [+ res]); A,C are [M,128], W [128,128] ----
// BM=64, BN=128 (full), BK=16, 256 threads, 8x4 register tile per thread.
// As stored TRANSPOSED [k][m] (pad 68) so the inner loop reads A via 2x ds_read_b128
// (half-wave same-address broadcast, conflict-free) instead of 8x ds_read_b32.
// NOTE: A and C deliberately NOT __restrict__ — GEMM1 runs in place (each block
// reads only its own 64 rows and writes them only in the epilogue).

__global__ __launch_bounds__(256) void mlp_gemm(const float* A,
                                                const float* __restrict__ W,
                                                const float* __restrict__ bias,
                                                const float* __restrict__ res,
                                                float* C) {
  __shared__ __align__(16) float As[16][68];      // [k][m], pad 68: 2-way write alias (free)
  __shared__ __align__(16) float Ws[16][128];     // [k][j]
  int tid = threadIdx.x;
  int row0 = blockIdx.x * 64;
  int jt = tid & 31;       // j tile: 4 cols at jt*4
  int mt = tid >> 5;       // m tile: 8 rows at mt*8
  int am = tid >> 2, ak = (tid & 3) * 4;          // A staging: 1 float4/thread
  int wk = tid >> 5, wj = (tid & 31) * 4;         // W staging: 2 float4/thread
  float acc[8][4];
#pragma unroll
  for (int a = 0; a < 8; ++a)
#pragma unroll
    for (int b = 0; b < 4; ++b) acc[a][b] = 0.f;

  for (int k0 = 0; k0 < HID; k0 += 16) {
    int arow = row0 + am;
    float4 av = make_float4(0.f, 0.f, 0.f, 0.f);
    if (arow < N_NODES) av = *(const float4*)(A + (size_t)arow * HID + k0 + ak);
    float4 w0 = *(const float4*)(W + (size_t)(k0 + wk) * HID + wj);
    float4 w1 = *(const float4*)(W + (size_t)(k0 + wk + 8) * HID + wj);
    __syncthreads();
    As[ak + 0][am] = av.x;
    As[ak + 1][am] = av.y;
    As[ak + 2][am] = av.z;
    As[ak + 3][am] = av.w;
    *(float4*)&Ws[wk][wj] = w0;
    *(float4*)&Ws[wk + 8][wj] = w1;
    __syncthreads();
#pragma unroll
    for (int k = 0; k < 16; ++k) {
      float4 wv = *(const float4*)&Ws[k][jt * 4];
      float4 a0 = *(const float4*)&As[k][mt * 8];
      float4 a1 = *(const float4*)&As[k][mt * 8 + 4];
      float am_[8] = {a0.x, a0.y, a0.z, a0.w, a1.x, a1.y, a1.z, a1.w};
#pragma unroll
      for (int mm = 0; mm < 8; ++mm) {
        acc[mm][0] += am_[mm] * wv.x;
        acc[mm][1] += am_[mm] * wv.y;
        acc[mm][2] += am_[mm] * wv.z;
        acc[mm][3] += am_[mm] * wv.w;
      }
    }
  }

  float4 bv = *(const float4*)(bias + jt * 4);
#pragma unroll
  for (int mm = 0; mm < 8; ++mm) {
    int row = row0 + mt * 8 + mm;
    if (row < N_NODES) {
      float4 o;
      o.x = acc[mm][0] + bv.x;
      o.y = acc[mm][1] + bv.y;
      o.z = acc[mm][2] + bv.z;
      o.w = acc[mm][3] + bv.w;
      if (res) {
        float4 rv = *(const float4*)(res + (size_t)row * HID + jt * 4);
        o.x += rv.x; o.y += rv.y; o.z += rv.z; o.w += rv.w;
      }
      o.x = o.x > 0.f ? o.x : 0.f;
      o.y = o.y > 0.f ? o.y : 0.f;
      o.z = o.z > 0.f ? o.z : 0.f;
      o.w = o.w > 0.f ? o.w : 0.f;
      *(float4*)(C + (size_t)row * HID + jt * 4) = o;
    }
  }
}

// ---------------- pooling (batch is sorted) ----------------

__global__ __launch_bounds__(128) void pool_kernel(const float* __restrict__ h,
                                                   const int* __restrict__ batch,
                                                   float* __restrict__ pooled) {
  int j = threadIdx.x;
  int n0 = blockIdx.x * 256;
  int nend = n0 + 256;
  if (nend > N_NODES) nend = N_NODES;
  int cur = batch[n0];
  float acc = 0.f;
  for (int n = n0; n < nend; ++n) {
    int b = batch[n];
    if (b != cur) {
      atomicAdd(&pooled[cur * HID + j], acc);
      acc = 0.f;
      cur = b;
    }
    acc += h[(size_t)n * HID + j];
  }
  atomicAdd(&pooled[cur * HID + j], acc);
}

// ---------------- final: out[g] = pooled[g] . ffn_w + ffn_b ----------------

__global__ __launch_bounds__(128) void final_kernel(const float* __restrict__ pooled,
                                                    const float* __restrict__ fw,
                                                    const float* __restrict__ fb,
                                                    float* __restrict__ out) {
  int g = blockIdx.x;
  int j = threadIdx.x;
  float v = pooled[g * HID + j] * fw[j];
#pragma unroll
  for (int off = 32; off > 0; off >>= 1) v += __shfl_down(v, off, 64);
  __shared__ float tmp[2];
  if ((j & 63) == 0) tmp[j >> 6] = v;
  __syncthreads();
  if (j == 0) out[g] = tmp[0] + tmp[1] + fb[0];
}

// ---------------- launch ----------------

extern "C" void kernel_launch(void* const* d_in, const int* in_sizes, int n_in,
                              void* d_out, int out_size, void* d_ws, size_t ws_size,
                              hipStream_t stream) {
  const float* x = (const float*)d_in[0];
  const int* edge_index = (const int*)d_in[1];
  const float* edge_attr = (const float*)d_in[2];
  const int* batch = (const int*)d_in[3];
  const float* init_w = (const float*)d_in[4];
  const float* init_b = (const float*)d_in[5];
  const float* edge_w = (const float*)d_in[6];
  const float* edge_b = (const float*)d_in[7];
  const float* mlp_w1 = (const float*)d_in[8];
  const float* mlp_b1 = (const float*)d_in[9];
  const float* mlp_w2 = (const float*)d_in[10];
  const float* mlp_b2 = (const float*)d_in[11];
  const float* ffn_w = (const float*)d_in[12];
  const float* ffn_b = (const float*)d_in[13];

  const int* srcp = edge_index;
  const int* dstp = edge_index + N_EDGES;

  char* ws = (char*)d_ws;
  auto alloc = [&](size_t bytes) {
    char* p = ws;
    ws += (bytes + 255) & ~(size_t)255;
    return p;
  };
  float* h = (float*)alloc((size_t)N_NODES * HID * 4);
  float* h0 = (float*)alloc((size_t)N_NODES * HID * 4);
  float* z1 = (float*)alloc((size_t)N_NODES * HID * 4);
  int* row_ptr = (int*)alloc((size_t)(N_NODES + 1) * 4);
  int* cursor = (int*)alloc((size_t)N_NODES * 4);
  int* counts = (int*)alloc((size_t)N_NODES * 4);
  int* bsums = (int*)alloc((size_t)SCAN_BLOCKS * 4);
  int* boff = (int*)alloc((size_t)SCAN_BLOCKS * 4);
  int* src_perm = (int*)alloc((size_t)N_EDGES * 4);
  float* ea_perm = (float*)alloc((size_t)N_EDGES * F_EDGE * 4);
  float* pooled = (float*)alloc((size_t)N_GRAPHS * HID * 4);

  hipMemsetAsync(counts, 0, (size_t)N_NODES * 4, stream);
  hipMemsetAsync(pooled, 0, (size_t)N_GRAPHS * HID * 4, stream);

  hist_kernel<<<(N_EDGES + 255) / 256, 256, 0, stream>>>(dstp, counts);
  scan_sum_kernel<<<SCAN_BLOCKS, 256, 0, stream>>>(counts, bsums);
  scan_mid_kernel<<<1, 256, 0, stream>>>(bsums, boff, row_ptr);
  scan_write_kernel<<<SCAN_BLOCKS, 256, 0, stream>>>(counts, boff, row_ptr, cursor);
  scatter_kernel<<<(N_EDGES + 255) / 256, 256, 0, stream>>>(srcp, dstp, edge_attr,
                                                            cursor, src_perm, ea_perm);

  init_kernel<<<N_NODES, 128, 0, stream>>>(x, init_w, init_b, h, h0);

  for (int d = 0; d < DEPTH; ++d) {
    agg_kernel<<<(N_NODES + NODES_PER_BLOCK - 1) / NODES_PER_BLOCK, 128, 0, stream>>>(
        h, src_perm, ea_perm, row_ptr, edge_w + (size_t)d * F_EDGE * HID,
        edge_b + (size_t)d * HID, z1);
    mlp_gemm<<<(N_NODES + 63) / 64, 256, 0, stream>>>(
        z1, mlp_w1 + (size_t)d * HID * HID, mlp_b1 + (size_t)d * HID, nullptr, z1);
    mlp_gemm<<<(N_NODES + 63) / 64, 256, 0, stream>>>(
        z1, mlp_w2 + (size_t)d * HID * HID, mlp_b2 + (size_t)d * HID, h0, h);
  }

  pool_kernel<<<(N_NODES + 255) / 256, 128, 0, stream>>>(h, batch, pooled);
  final_kernel<<<N_GRAPHS, 128, 0, stream>>>(pooled, ffn_w, ffn_b, (float*)d_out);
}

// Round 4
// 822.484 us; speedup vs baseline: 1.6761x; 1.1642x over previous
//
#include <hip/hip_runtime.h>

#define N_NODES 50000
#define N_EDGES 800000
#define F_NODE 32
#define F_EDGE 16
#define HID 128
#define DEPTH 4
#define N_GRAPHS 128

#define SCAN_BLOCKS ((N_NODES + 255) / 256)  // 196
#define NSTRIPS ((N_NODES + 31) / 32)        // 1563

using short8 = __attribute__((ext_vector_type(8))) short;
using f32x4 = __attribute__((ext_vector_type(4))) float;

__device__ __forceinline__ float bf2f(unsigned short u) {
  return __uint_as_float((unsigned int)u << 16);
}
__device__ __forceinline__ unsigned short f2bf(float f) {
  unsigned int u = __float_as_uint(f);
  u += 0x7fffu + ((u >> 16) & 1u);  // round-to-nearest-even (no NaN in data)
  return (unsigned short)(u >> 16);
}

// ---------------- CSR build (by dst) ----------------

__global__ void hist_kernel(const int* __restrict__ dst, int* __restrict__ counts) {
  int e = blockIdx.x * blockDim.x + threadIdx.x;
  if (e < N_EDGES) atomicAdd(&counts[dst[e]], 1);
}

__device__ __forceinline__ int wave_incl_scan(int v, int lane) {
#pragma unroll
  for (int off = 1; off < 64; off <<= 1) {
    int u = __shfl_up(v, off, 64);
    if (lane >= off) v += u;
  }
  return v;
}

__global__ __launch_bounds__(256) void scan_sum_kernel(const int* __restrict__ counts,
                                                       int* __restrict__ bsums) {
  int i = blockIdx.x * 256 + threadIdx.x;
  int v = (i < N_NODES) ? counts[i] : 0;
  int lane = threadIdx.x & 63, wid = threadIdx.x >> 6;
#pragma unroll
  for (int off = 32; off > 0; off >>= 1) v += __shfl_down(v, off, 64);
  __shared__ int ws[4];
  if (lane == 0) ws[wid] = v;
  __syncthreads();
  if (threadIdx.x == 0) bsums[blockIdx.x] = ws[0] + ws[1] + ws[2] + ws[3];
}

__global__ __launch_bounds__(256) void scan_mid_kernel(const int* __restrict__ bsums,
                                                       int* __restrict__ boff,
                                                       int* __restrict__ row_ptr) {
  int t = threadIdx.x;
  int v = (t < SCAN_BLOCKS) ? bsums[t] : 0;
  int lane = t & 63, wid = t >> 6;
  int s = wave_incl_scan(v, lane);
  __shared__ int wsum[4];
  if (lane == 63) wsum[wid] = s;
  __syncthreads();
  int add = 0;
  for (int w = 0; w < wid; ++w) add += wsum[w];
  s += add;
  if (t < SCAN_BLOCKS) boff[t] = s - v;
  if (t == SCAN_BLOCKS - 1) row_ptr[N_NODES] = s;
}

__global__ __launch_bounds__(256) void scan_write_kernel(const int* __restrict__ counts,
                                                         const int* __restrict__ boff,
                                                         int* __restrict__ row_ptr,
                                                         int* __restrict__ cursor) {
  int i = blockIdx.x * 256 + threadIdx.x;
  int v = (i < N_NODES) ? counts[i] : 0;
  int lane = threadIdx.x & 63, wid = threadIdx.x >> 6;
  int s = wave_incl_scan(v, lane);
  __shared__ int wsum[4];
  if (lane == 63) wsum[wid] = s;
  __syncthreads();
  int add = boff[blockIdx.x];
  for (int w = 0; w < wid; ++w) add += wsum[w];
  int excl = s - v + add;
  if (i < N_NODES) {
    row_ptr[i] = excl;
    cursor[i] = excl;
  }
}

// ---- scatter: materialize src/edge_attr in dst-sorted order ----

__global__ void scatter_kernel(const int* __restrict__ src, const int* __restrict__ dst,
                               const float* __restrict__ edge_attr,
                               int* __restrict__ cursor, int* __restrict__ src_perm,
                               float* __restrict__ ea_perm) {
  int e = blockIdx.x * blockDim.x + threadIdx.x;
  if (e < N_EDGES) {
    int pos = atomicAdd(&cursor[dst[e]], 1);
    src_perm[pos] = src[e];
    const float4* in4 = (const float4*)(edge_attr + (size_t)e * F_EDGE);
    float4 a = in4[0], b = in4[1], c = in4[2], d = in4[3];
    float4* out4 = (float4*)(ea_perm + (size_t)pos * F_EDGE);
    out4[0] = a; out4[1] = b; out4[2] = c; out4[3] = d;
  }
}

// ---- weight repack: W[k][n] fp32 -> bf16 MFMA B-frag order ----
// frag f = t*4+k0 (t: 16-col tile, k0: 32-k step); lane l holds
// B[k = k0*32 + (l>>4)*8 + j][n = t*16 + (l&15)], j=0..7.

__global__ __launch_bounds__(256) void repack_w(const float* __restrict__ w1,
                                                const float* __restrict__ w2,
                                                unsigned short* __restrict__ wfrag) {
  int idx = blockIdx.x * 256 + threadIdx.x;
  if (idx >= 8 * 16384) return;
  int g = idx >> 14;
  int rem = idx & 16383;
  int f = rem >> 9;
  int lane = (rem >> 3) & 63;
  int j = rem & 7;
  int t = f >> 2, k0 = f & 3;
  int k = k0 * 32 + (lane >> 4) * 8 + j;
  int n = t * 16 + (lane & 15);
  int d = g >> 1;
  const float* W = (g & 1) ? (w2 + (size_t)d * HID * HID) : (w1 + (size_t)d * HID * HID);
  wfrag[idx] = f2bf(W[k * HID + n]);
}

// ---------------- init: h = relu(x @ init_w + init_b) -> bf16 h, h0 ----------------

__global__ __launch_bounds__(128) void init_kernel(const float* __restrict__ x,
                                                   const float* __restrict__ Wi,
                                                   const float* __restrict__ bi,
                                                   unsigned short* __restrict__ h,
                                                   unsigned short* __restrict__ h0) {
  int node = blockIdx.x;
  int j = threadIdx.x;
  __shared__ float xs[F_NODE];
  if (j < F_NODE) xs[j] = x[node * F_NODE + j];
  __syncthreads();
  float acc = bi[j];
#pragma unroll
  for (int k = 0; k < F_NODE; ++k) acc += xs[k] * Wi[k * HID + j];
  float v = acc > 0.f ? acc : 0.f;
  unsigned short b = f2bf(v);
  h[(size_t)node * HID + j] = b;
  h0[(size_t)node * HID + j] = b;
}

// ---- aggregation: z[n] = h[n] + sum relu(h[src] + ea @ We + be), h in bf16 ----

#define NODES_PER_BLOCK 8

__device__ __forceinline__ float edge_mlp(const float4* __restrict__ ea,
                                          const float w[16], float bj) {
  float4 a0 = ea[0], a1 = ea[1], a2 = ea[2], a3 = ea[3];
  float ev = bj;
  ev += a0.x * w[0] + a0.y * w[1] + a0.z * w[2] + a0.w * w[3];
  ev += a1.x * w[4] + a1.y * w[5] + a1.z * w[6] + a1.w * w[7];
  ev += a2.x * w[8] + a2.y * w[9] + a2.z * w[10] + a2.w * w[11];
  ev += a3.x * w[12] + a3.y * w[13] + a3.z * w[14] + a3.w * w[15];
  return ev;
}

__global__ __launch_bounds__(128) void agg_kernel(const unsigned short* __restrict__ h,
                                                  const int* __restrict__ src_perm,
                                                  const float* __restrict__ ea_perm,
                                                  const int* __restrict__ row_ptr,
                                                  const float* __restrict__ We,
                                                  const float* __restrict__ be,
                                                  unsigned short* __restrict__ z) {
  int j = threadIdx.x;
  float w[16];
#pragma unroll
  for (int t = 0; t < F_EDGE; ++t) w[t] = We[t * HID + j];
  float bj = be[j];
  int n0 = blockIdx.x * NODES_PER_BLOCK;
  int n1 = n0 + NODES_PER_BLOCK;
  if (n1 > N_NODES) n1 = N_NODES;
  for (int node = n0; node < n1; ++node) {
    int beg = row_ptr[node], end = row_ptr[node + 1];
    float hn = bf2f(h[(size_t)node * HID + j]);
    float acc = 0.f;
    int i = beg;
    for (; i + 4 <= end; i += 4) {
      int s0 = src_perm[i + 0];
      int s1 = src_perm[i + 1];
      int s2 = src_perm[i + 2];
      int s3 = src_perm[i + 3];
      unsigned short hu0 = h[(size_t)s0 * HID + j];
      unsigned short hu1 = h[(size_t)s1 * HID + j];
      unsigned short hu2 = h[(size_t)s2 * HID + j];
      unsigned short hu3 = h[(size_t)s3 * HID + j];
      const float4* ea = (const float4*)(ea_perm + (size_t)i * F_EDGE);
      float ev0 = edge_mlp(ea + 0, w, bj);
      float ev1 = edge_mlp(ea + 4, w, bj);
      float ev2 = edge_mlp(ea + 8, w, bj);
      float ev3 = edge_mlp(ea + 12, w, bj);
      float m0 = bf2f(hu0) + ev0, m1 = bf2f(hu1) + ev1;
      float m2 = bf2f(hu2) + ev2, m3 = bf2f(hu3) + ev3;
      acc += (m0 > 0.f ? m0 : 0.f) + (m1 > 0.f ? m1 : 0.f) +
             (m2 > 0.f ? m2 : 0.f) + (m3 > 0.f ? m3 : 0.f);
    }
    for (; i < end; ++i) {
      int s = src_perm[i];
      float hv = bf2f(h[(size_t)s * HID + j]);
      const float4* ea = (const float4*)(ea_perm + (size_t)i * F_EDGE);
      float m = hv + edge_mlp(ea, w, bj);
      acc += (m > 0.f ? m : 0.f);
    }
    z[(size_t)node * HID + j] = f2bf(hn + acc);
  }
}

// ---- MFMA GEMM: C = relu(A @ W + bias [+ res]); A,C bf16 [M,128], W pre-fragged ----
// 256 threads = 4 waves: wave covers 16 rows x 64 cols (rowHalf x colHalf).
// B-frags (16 per wave) persistent in VGPRs; A-frags 16B/lane straight from global.
// A-frag: lane holds A[m=lane&15][k=quad*8+j]; C/D: col=lane&15, row=quad*4+reg.

__global__ __launch_bounds__(256) void mfma_gemm(const unsigned short* __restrict__ A,
                                                 const unsigned short* __restrict__ Wfrag,
                                                 const float* __restrict__ bias,
                                                 const unsigned short* __restrict__ res,
                                                 unsigned short* __restrict__ Cout) {
  int tid = threadIdx.x;
  int lane = tid & 63;
  int wave = tid >> 6;
  int rowHalf = wave >> 1;   // 0/1 -> +0/+16 rows within strip
  int colHalf = wave & 1;    // 0/1 -> cols 0-63 / 64-127
  int m15 = lane & 15, quad = lane >> 4;

  short8 b[4][4];
#pragma unroll
  for (int t = 0; t < 4; ++t)
#pragma unroll
    for (int k0 = 0; k0 < 4; ++k0)
      b[t][k0] = *(const short8*)(Wfrag + (((size_t)(colHalf * 4 + t) * 4 + k0) * 64 + lane) * 8);

  float bsv[4];
#pragma unroll
  for (int t = 0; t < 4; ++t) bsv[t] = bias[(colHalf * 4 + t) * 16 + m15];

  for (int s = blockIdx.x; s < NSTRIPS; s += gridDim.x) {
    int row0 = s * 32 + rowHalf * 16;
    int arow = row0 + m15;
    int rc = arow < N_NODES ? arow : N_NODES - 1;
    const unsigned short* ap = A + (size_t)rc * HID + quad * 8;
    short8 a0 = *(const short8*)(ap + 0);
    short8 a1 = *(const short8*)(ap + 32);
    short8 a2 = *(const short8*)(ap + 64);
    short8 a3 = *(const short8*)(ap + 96);
    f32x4 acc[4];
#pragma unroll
    for (int t = 0; t < 4; ++t) acc[t] = (f32x4){0.f, 0.f, 0.f, 0.f};
#pragma unroll
    for (int t = 0; t < 4; ++t) {
      acc[t] = __builtin_amdgcn_mfma_f32_16x16x32_bf16(a0, b[t][0], acc[t], 0, 0, 0);
      acc[t] = __builtin_amdgcn_mfma_f32_16x16x32_bf16(a1, b[t][1], acc[t], 0, 0, 0);
      acc[t] = __builtin_amdgcn_mfma_f32_16x16x32_bf16(a2, b[t][2], acc[t], 0, 0, 0);
      acc[t] = __builtin_amdgcn_mfma_f32_16x16x32_bf16(a3, b[t][3], acc[t], 0, 0, 0);
    }
#pragma unroll
    for (int t = 0; t < 4; ++t) {
      int col = (colHalf * 4 + t) * 16 + m15;
#pragma unroll
      for (int r = 0; r < 4; ++r) {
        int row = row0 + quad * 4 + r;
        if (row < N_NODES) {
          float v = acc[t][r] + bsv[t];
          if (res) v += bf2f(res[(size_t)row * HID + col]);
          v = v > 0.f ? v : 0.f;
          Cout[(size_t)row * HID + col] = f2bf(v);
        }
      }
    }
  }
}

// ---------------- pooling (batch is sorted), h in bf16 ----------------

__global__ __launch_bounds__(128) void pool_kernel(const unsigned short* __restrict__ h,
                                                   const int* __restrict__ batch,
                                                   float* __restrict__ pooled) {
  int j = threadIdx.x;
  int n0 = blockIdx.x * 256;
  int nend = n0 + 256;
  if (nend > N_NODES) nend = N_NODES;
  int cur = batch[n0];
  float acc = 0.f;
  for (int n = n0; n < nend; ++n) {
    int b = batch[n];
    if (b != cur) {
      atomicAdd(&pooled[cur * HID + j], acc);
      acc = 0.f;
      cur = b;
    }
    acc += bf2f(h[(size_t)n * HID + j]);
  }
  atomicAdd(&pooled[cur * HID + j], acc);
}

// ---------------- final: out[g] = pooled[g] . ffn_w + ffn_b ----------------

__global__ __launch_bounds__(128) void final_kernel(const float* __restrict__ pooled,
                                                    const float* __restrict__ fw,
                                                    const float* __restrict__ fb,
                                                    float* __restrict__ out) {
  int g = blockIdx.x;
  int j = threadIdx.x;
  float v = pooled[g * HID + j] * fw[j];
#pragma unroll
  for (int off = 32; off > 0; off >>= 1) v += __shfl_down(v, off, 64);
  __shared__ float tmp[2];
  if ((j & 63) == 0) tmp[j >> 6] = v;
  __syncthreads();
  if (j == 0) out[g] = tmp[0] + tmp[1] + fb[0];
}

// ---------------- launch ----------------

extern "C" void kernel_launch(void* const* d_in, const int* in_sizes, int n_in,
                              void* d_out, int out_size, void* d_ws, size_t ws_size,
                              hipStream_t stream) {
  const float* x = (const float*)d_in[0];
  const int* edge_index = (const int*)d_in[1];
  const float* edge_attr = (const float*)d_in[2];
  const int* batch = (const int*)d_in[3];
  const float* init_w = (const float*)d_in[4];
  const float* init_b = (const float*)d_in[5];
  const float* edge_w = (const float*)d_in[6];
  const float* edge_b = (const float*)d_in[7];
  const float* mlp_w1 = (const float*)d_in[8];
  const float* mlp_b1 = (const float*)d_in[9];
  const float* mlp_w2 = (const float*)d_in[10];
  const float* mlp_b2 = (const float*)d_in[11];
  const float* ffn_w = (const float*)d_in[12];
  const float* ffn_b = (const float*)d_in[13];

  const int* srcp = edge_index;
  const int* dstp = edge_index + N_EDGES;

  char* ws = (char*)d_ws;
  auto alloc = [&](size_t bytes) {
    char* p = ws;
    ws += (bytes + 255) & ~(size_t)255;
    return p;
  };
  unsigned short* h_bf = (unsigned short*)alloc((size_t)N_NODES * HID * 2);
  unsigned short* h0_bf = (unsigned short*)alloc((size_t)N_NODES * HID * 2);
  unsigned short* z_bf = (unsigned short*)alloc((size_t)N_NODES * HID * 2);
  unsigned short* z1_bf = (unsigned short*)alloc((size_t)N_NODES * HID * 2);
  unsigned short* wfrag = (unsigned short*)alloc((size_t)8 * 16384 * 2);
  int* row_ptr = (int*)alloc((size_t)(N_NODES + 1) * 4);
  int* cursor = (int*)alloc((size_t)N_NODES * 4);
  int* counts = (int*)alloc((size_t)N_NODES * 4);
  int* bsums = (int*)alloc((size_t)SCAN_BLOCKS * 4);
  int* boff = (int*)alloc((size_t)SCAN_BLOCKS * 4);
  int* src_perm = (int*)alloc((size_t)N_EDGES * 4);
  float* ea_perm = (float*)alloc((size_t)N_EDGES * F_EDGE * 4);
  float* pooled = (float*)alloc((size_t)N_GRAPHS * HID * 4);

  hipMemsetAsync(counts, 0, (size_t)N_NODES * 4, stream);
  hipMemsetAsync(pooled, 0, (size_t)N_GRAPHS * HID * 4, stream);

  hist_kernel<<<(N_EDGES + 255) / 256, 256, 0, stream>>>(dstp, counts);
  scan_sum_kernel<<<SCAN_BLOCKS, 256, 0, stream>>>(counts, bsums);
  scan_mid_kernel<<<1, 256, 0, stream>>>(bsums, boff, row_ptr);
  scan_write_kernel<<<SCAN_BLOCKS, 256, 0, stream>>>(counts, boff, row_ptr, cursor);
  scatter_kernel<<<(N_EDGES + 255) / 256, 256, 0, stream>>>(srcp, dstp, edge_attr,
                                                            cursor, src_perm, ea_perm);
  repack_w<<<512, 256, 0, stream>>>(mlp_w1, mlp_w2, wfrag);

  init_kernel<<<N_NODES, 128, 0, stream>>>(x, init_w, init_b, h_bf, h0_bf);

  for (int d = 0; d < DEPTH; ++d) {
    agg_kernel<<<(N_NODES + NODES_PER_BLOCK - 1) / NODES_PER_BLOCK, 128, 0, stream>>>(
        h_bf, src_perm, ea_perm, row_ptr, edge_w + (size_t)d * F_EDGE * HID,
        edge_b + (size_t)d * HID, z_bf);
    mfma_gemm<<<782, 256, 0, stream>>>(z_bf, wfrag + (size_t)(2 * d) * 16384,
                                       mlp_b1 + (size_t)d * HID, nullptr, z1_bf);
    mfma_gemm<<<782, 256, 0, stream>>>(z1_bf, wfrag + (size_t)(2 * d + 1) * 16384,
                                       mlp_b2 + (size_t)d * HID, h0_bf, h_bf);
  }

  pool_kernel<<<(N_NODES + 255) / 256, 128, 0, stream>>>(h_bf, batch, pooled);
  final_kernel<<<N_GRAPHS, 128, 0, stream>>>(pooled, ffn_w, ffn_b, (float*)d_out);
}

// Round 5
// 731.406 us; speedup vs baseline: 1.8848x; 1.1245x over previous
//
#include <hip/hip_runtime.h>

#define N_NODES 50000
#define N_EDGES 800000
#define F_NODE 32
#define F_EDGE 16
#define HID 128
#define DEPTH 4
#define N_GRAPHS 128

#define SCAN_BLOCKS ((N_NODES + 255) / 256)  // 196
#define NSTRIPS ((N_NODES + 31) / 32)        // 1563

using short8 = __attribute__((ext_vector_type(8))) short;
using f32x4 = __attribute__((ext_vector_type(4))) float;
using v2f = __attribute__((ext_vector_type(2))) float;

__device__ __forceinline__ float bf2f(unsigned short u) {
  return __uint_as_float((unsigned int)u << 16);
}
__device__ __forceinline__ unsigned short f2bf(float f) {
  unsigned int u = __float_as_uint(f);
  u += 0x7fffu + ((u >> 16) & 1u);  // round-to-nearest-even (no NaN in data)
  return (unsigned short)(u >> 16);
}
__device__ __forceinline__ v2f splat2(float s) { return (v2f){s, s}; }
__device__ __forceinline__ v2f unpack2(unsigned int u) {
  v2f r;
  r.x = __uint_as_float(u << 16);           // low ushort  -> col 2l
  r.y = __uint_as_float(u & 0xffff0000u);   // high ushort -> col 2l+1
  return r;
}
__device__ __forceinline__ unsigned int pack2(v2f v) {
  return ((unsigned int)f2bf(v.y) << 16) | (unsigned int)f2bf(v.x);
}

// ---------------- CSR build (by dst) ----------------

__global__ void hist_kernel(const int* __restrict__ dst, int* __restrict__ counts) {
  int e = blockIdx.x * blockDim.x + threadIdx.x;
  if (e < N_EDGES) atomicAdd(&counts[dst[e]], 1);
}

__device__ __forceinline__ int wave_incl_scan(int v, int lane) {
#pragma unroll
  for (int off = 1; off < 64; off <<= 1) {
    int u = __shfl_up(v, off, 64);
    if (lane >= off) v += u;
  }
  return v;
}

__global__ __launch_bounds__(256) void scan_sum_kernel(const int* __restrict__ counts,
                                                       int* __restrict__ bsums) {
  int i = blockIdx.x * 256 + threadIdx.x;
  int v = (i < N_NODES) ? counts[i] : 0;
  int lane = threadIdx.x & 63, wid = threadIdx.x >> 6;
#pragma unroll
  for (int off = 32; off > 0; off >>= 1) v += __shfl_down(v, off, 64);
  __shared__ int ws[4];
  if (lane == 0) ws[wid] = v;
  __syncthreads();
  if (threadIdx.x == 0) bsums[blockIdx.x] = ws[0] + ws[1] + ws[2] + ws[3];
}

__global__ __launch_bounds__(256) void scan_mid_kernel(const int* __restrict__ bsums,
                                                       int* __restrict__ boff,
                                                       int* __restrict__ row_ptr) {
  int t = threadIdx.x;
  int v = (t < SCAN_BLOCKS) ? bsums[t] : 0;
  int lane = t & 63, wid = t >> 6;
  int s = wave_incl_scan(v, lane);
  __shared__ int wsum[4];
  if (lane == 63) wsum[wid] = s;
  __syncthreads();
  int add = 0;
  for (int w = 0; w < wid; ++w) add += wsum[w];
  s += add;
  if (t < SCAN_BLOCKS) boff[t] = s - v;
  if (t == SCAN_BLOCKS - 1) row_ptr[N_NODES] = s;
}

__global__ __launch_bounds__(256) void scan_write_kernel(const int* __restrict__ counts,
                                                         const int* __restrict__ boff,
                                                         int* __restrict__ row_ptr,
                                                         int* __restrict__ cursor) {
  int i = blockIdx.x * 256 + threadIdx.x;
  int v = (i < N_NODES) ? counts[i] : 0;
  int lane = threadIdx.x & 63, wid = threadIdx.x >> 6;
  int s = wave_incl_scan(v, lane);
  __shared__ int wsum[4];
  if (lane == 63) wsum[wid] = s;
  __syncthreads();
  int add = boff[blockIdx.x];
  for (int w = 0; w < wid; ++w) add += wsum[w];
  int excl = s - v + add;
  if (i < N_NODES) {
    row_ptr[i] = excl;
    cursor[i] = excl;
  }
}

// ---- scatter: materialize src/edge_attr in dst-sorted order ----

__global__ void scatter_kernel(const int* __restrict__ src, const int* __restrict__ dst,
                               const float* __restrict__ edge_attr,
                               int* __restrict__ cursor, int* __restrict__ src_perm,
                               float* __restrict__ ea_perm) {
  int e = blockIdx.x * blockDim.x + threadIdx.x;
  if (e < N_EDGES) {
    int pos = atomicAdd(&cursor[dst[e]], 1);
    src_perm[pos] = src[e];
    const float4* in4 = (const float4*)(edge_attr + (size_t)e * F_EDGE);
    float4 a = in4[0], b = in4[1], c = in4[2], d = in4[3];
    float4* out4 = (float4*)(ea_perm + (size_t)pos * F_EDGE);
    out4[0] = a; out4[1] = b; out4[2] = c; out4[3] = d;
  }
}

// ---- weight repack: W[k][n] fp32 -> bf16 MFMA B-frag order ----
// frag f = t*4+k0 (t: 16-col tile, k0: 32-k step); lane l holds
// B[k = k0*32 + (l>>4)*8 + j][n = t*16 + (l&15)], j=0..7.

__global__ __launch_bounds__(256) void repack_w(const float* __restrict__ w1,
                                                const float* __restrict__ w2,
                                                unsigned short* __restrict__ wfrag) {
  int idx = blockIdx.x * 256 + threadIdx.x;
  if (idx >= 8 * 16384) return;
  int g = idx >> 14;
  int rem = idx & 16383;
  int f = rem >> 9;
  int lane = (rem >> 3) & 63;
  int j = rem & 7;
  int t = f >> 2, k0 = f & 3;
  int k = k0 * 32 + (lane >> 4) * 8 + j;
  int n = t * 16 + (lane & 15);
  int d = g >> 1;
  const float* W = (g & 1) ? (w2 + (size_t)d * HID * HID) : (w1 + (size_t)d * HID * HID);
  wfrag[idx] = f2bf(W[k * HID + n]);
}

// ---------------- init: h = relu(x @ init_w + init_b) -> bf16 h, h0 ----------------

__global__ __launch_bounds__(128) void init_kernel(const float* __restrict__ x,
                                                   const float* __restrict__ Wi,
                                                   const float* __restrict__ bi,
                                                   unsigned short* __restrict__ h,
                                                   unsigned short* __restrict__ h0) {
  int node = blockIdx.x;
  int j = threadIdx.x;
  __shared__ float xs[F_NODE];
  if (j < F_NODE) xs[j] = x[node * F_NODE + j];
  __syncthreads();
  float acc = bi[j];
#pragma unroll
  for (int k = 0; k < F_NODE; ++k) acc += xs[k] * Wi[k * HID + j];
  float v = acc > 0.f ? acc : 0.f;
  unsigned short b = f2bf(v);
  h[(size_t)node * HID + j] = b;
  h0[(size_t)node * HID + j] = b;
}

// ---- aggregation: z[n] = h[n] + sum relu(h[src] + ea @ We + be) ----
// 64-thread blocks; lane l handles cols {2l, 2l+1} as packed fp32 (v_pk_fma_f32).
// blockIdx-only node derivation keeps src_perm/ea_perm loads scalarized.

#define NODES_PER_BLOCK 8

__device__ __forceinline__ v2f edge_mlp2(const float4* __restrict__ ea,
                                         const v2f w[16], v2f ev) {
  float4 a0 = ea[0], a1 = ea[1], a2 = ea[2], a3 = ea[3];
  ev = __builtin_elementwise_fma(splat2(a0.x), w[0], ev);
  ev = __builtin_elementwise_fma(splat2(a0.y), w[1], ev);
  ev = __builtin_elementwise_fma(splat2(a0.z), w[2], ev);
  ev = __builtin_elementwise_fma(splat2(a0.w), w[3], ev);
  ev = __builtin_elementwise_fma(splat2(a1.x), w[4], ev);
  ev = __builtin_elementwise_fma(splat2(a1.y), w[5], ev);
  ev = __builtin_elementwise_fma(splat2(a1.z), w[6], ev);
  ev = __builtin_elementwise_fma(splat2(a1.w), w[7], ev);
  ev = __builtin_elementwise_fma(splat2(a2.x), w[8], ev);
  ev = __builtin_elementwise_fma(splat2(a2.y), w[9], ev);
  ev = __builtin_elementwise_fma(splat2(a2.z), w[10], ev);
  ev = __builtin_elementwise_fma(splat2(a2.w), w[11], ev);
  ev = __builtin_elementwise_fma(splat2(a3.x), w[12], ev);
  ev = __builtin_elementwise_fma(splat2(a3.y), w[13], ev);
  ev = __builtin_elementwise_fma(splat2(a3.z), w[14], ev);
  ev = __builtin_elementwise_fma(splat2(a3.w), w[15], ev);
  return ev;
}

__global__ __launch_bounds__(64) void agg_kernel(const unsigned short* __restrict__ h,
                                                 const int* __restrict__ src_perm,
                                                 const float* __restrict__ ea_perm,
                                                 const int* __restrict__ row_ptr,
                                                 const float* __restrict__ We,
                                                 const float* __restrict__ be,
                                                 unsigned short* __restrict__ z) {
  int l = threadIdx.x;  // 0..63
  const unsigned int* h32 = (const unsigned int*)h;
  unsigned int* z32 = (unsigned int*)z;
  v2f w[16];
#pragma unroll
  for (int t = 0; t < F_EDGE; ++t) {
    float2 wv = *(const float2*)(We + t * HID + 2 * l);
    w[t] = (v2f){wv.x, wv.y};
  }
  float2 bv = *(const float2*)(be + 2 * l);
  v2f bj = (v2f){bv.x, bv.y};
  int n0 = blockIdx.x * NODES_PER_BLOCK;
  int n1 = n0 + NODES_PER_BLOCK;
  if (n1 > N_NODES) n1 = N_NODES;
  for (int node = n0; node < n1; ++node) {
    int beg = row_ptr[node], end = row_ptr[node + 1];
    v2f hn = unpack2(h32[(size_t)node * 64 + l]);
    v2f acc = splat2(0.f);
    int i = beg;
    for (; i + 4 <= end; i += 4) {
      int s0 = src_perm[i + 0];
      int s1 = src_perm[i + 1];
      int s2 = src_perm[i + 2];
      int s3 = src_perm[i + 3];
      unsigned int g0 = h32[(size_t)s0 * 64 + l];
      unsigned int g1 = h32[(size_t)s1 * 64 + l];
      unsigned int g2 = h32[(size_t)s2 * 64 + l];
      unsigned int g3 = h32[(size_t)s3 * 64 + l];
      const float4* ea = (const float4*)(ea_perm + (size_t)i * F_EDGE);
      v2f ev0 = edge_mlp2(ea + 0, w, bj);
      v2f ev1 = edge_mlp2(ea + 4, w, bj);
      v2f ev2 = edge_mlp2(ea + 8, w, bj);
      v2f ev3 = edge_mlp2(ea + 12, w, bj);
      v2f m0 = unpack2(g0) + ev0;
      v2f m1 = unpack2(g1) + ev1;
      v2f m2 = unpack2(g2) + ev2;
      v2f m3 = unpack2(g3) + ev3;
      m0 = __builtin_elementwise_max(m0, splat2(0.f));
      m1 = __builtin_elementwise_max(m1, splat2(0.f));
      m2 = __builtin_elementwise_max(m2, splat2(0.f));
      m3 = __builtin_elementwise_max(m3, splat2(0.f));
      acc += m0 + m1 + m2 + m3;
    }
    for (; i < end; ++i) {
      int s = src_perm[i];
      unsigned int g = h32[(size_t)s * 64 + l];
      const float4* ea = (const float4*)(ea_perm + (size_t)i * F_EDGE);
      v2f m = unpack2(g) + edge_mlp2(ea, w, bj);
      m = __builtin_elementwise_max(m, splat2(0.f));
      acc += m;
    }
    z32[(size_t)node * 64 + l] = pack2(hn + acc);
  }
}

// ---- fused MLP: h = relu(relu(z@W1+b1)@W2+b2 + h0), per-depth, z1 via LDS ----
// 256 threads = 4 waves: wave covers 16 rows x 64 cols. Both W-frag sets in VGPRs.
// LDS tile [32][136] bf16: +8 pad keeps 16B alignment & conflict-free b128 reads.
// A-frag: lane holds A[m=lane&15][k=quad*8+j]; C/D: col=lane&15, row=quad*4+reg.

__global__ __launch_bounds__(256) void fused_mlp(const unsigned short* __restrict__ A,
                                                 const unsigned short* __restrict__ Wf1,
                                                 const unsigned short* __restrict__ Wf2,
                                                 const float* __restrict__ b1,
                                                 const float* __restrict__ b2,
                                                 const unsigned short* __restrict__ h0,
                                                 unsigned short* __restrict__ hout) {
  __shared__ unsigned short z1t[32][136];
  int tid = threadIdx.x;
  int lane = tid & 63;
  int wave = tid >> 6;
  int rowHalf = wave >> 1;
  int colHalf = wave & 1;
  int m15 = lane & 15, quad = lane >> 4;

  short8 bA[4][4], bB[4][4];
#pragma unroll
  for (int t = 0; t < 4; ++t)
#pragma unroll
    for (int k0 = 0; k0 < 4; ++k0) {
      size_t off = (((size_t)(colHalf * 4 + t) * 4 + k0) * 64 + lane) * 8;
      bA[t][k0] = *(const short8*)(Wf1 + off);
      bB[t][k0] = *(const short8*)(Wf2 + off);
    }
  float bs1[4], bs2[4];
#pragma unroll
  for (int t = 0; t < 4; ++t) {
    bs1[t] = b1[(colHalf * 4 + t) * 16 + m15];
    bs2[t] = b2[(colHalf * 4 + t) * 16 + m15];
  }

  for (int s = blockIdx.x; s < NSTRIPS; s += gridDim.x) {
    int row0 = s * 32 + rowHalf * 16;
    // ---- phase 1: z1 = relu(z @ W1 + b1) -> LDS ----
    int arow = row0 + m15;
    int rc = arow < N_NODES ? arow : N_NODES - 1;
    const unsigned short* ap = A + (size_t)rc * HID + quad * 8;
    short8 a0 = *(const short8*)(ap + 0);
    short8 a1 = *(const short8*)(ap + 32);
    short8 a2 = *(const short8*)(ap + 64);
    short8 a3 = *(const short8*)(ap + 96);
    f32x4 acc[4];
#pragma unroll
    for (int t = 0; t < 4; ++t) acc[t] = (f32x4){0.f, 0.f, 0.f, 0.f};
#pragma unroll
    for (int t = 0; t < 4; ++t) {
      acc[t] = __builtin_amdgcn_mfma_f32_16x16x32_bf16(a0, bA[t][0], acc[t], 0, 0, 0);
      acc[t] = __builtin_amdgcn_mfma_f32_16x16x32_bf16(a1, bA[t][1], acc[t], 0, 0, 0);
      acc[t] = __builtin_amdgcn_mfma_f32_16x16x32_bf16(a2, bA[t][2], acc[t], 0, 0, 0);
      acc[t] = __builtin_amdgcn_mfma_f32_16x16x32_bf16(a3, bA[t][3], acc[t], 0, 0, 0);
    }
#pragma unroll
    for (int t = 0; t < 4; ++t) {
      int col = (colHalf * 4 + t) * 16 + m15;
#pragma unroll
      for (int r = 0; r < 4; ++r) {
        float v = acc[t][r] + bs1[t];
        v = v > 0.f ? v : 0.f;
        z1t[rowHalf * 16 + quad * 4 + r][col] = f2bf(v);
      }
    }
    __syncthreads();
    // ---- phase 2: h = relu(z1 @ W2 + b2 + h0) ----
    const unsigned short* lp = &z1t[rowHalf * 16 + m15][quad * 8];
    short8 c0 = *(const short8*)(lp + 0);
    short8 c1 = *(const short8*)(lp + 32);
    short8 c2 = *(const short8*)(lp + 64);
    short8 c3 = *(const short8*)(lp + 96);
#pragma unroll
    for (int t = 0; t < 4; ++t) acc[t] = (f32x4){0.f, 0.f, 0.f, 0.f};
#pragma unroll
    for (int t = 0; t < 4; ++t) {
      acc[t] = __builtin_amdgcn_mfma_f32_16x16x32_bf16(c0, bB[t][0], acc[t], 0, 0, 0);
      acc[t] = __builtin_amdgcn_mfma_f32_16x16x32_bf16(c1, bB[t][1], acc[t], 0, 0, 0);
      acc[t] = __builtin_amdgcn_mfma_f32_16x16x32_bf16(c2, bB[t][2], acc[t], 0, 0, 0);
      acc[t] = __builtin_amdgcn_mfma_f32_16x16x32_bf16(c3, bB[t][3], acc[t], 0, 0, 0);
    }
#pragma unroll
    for (int t = 0; t < 4; ++t) {
      int col = (colHalf * 4 + t) * 16 + m15;
#pragma unroll
      for (int r = 0; r < 4; ++r) {
        int row = row0 + quad * 4 + r;
        if (row < N_NODES) {
          float v = acc[t][r] + bs2[t] + bf2f(h0[(size_t)row * HID + col]);
          v = v > 0.f ? v : 0.f;
          hout[(size_t)row * HID + col] = f2bf(v);
        }
      }
    }
    __syncthreads();  // LDS reused next strip
  }
}

// ---------------- pooling (batch is sorted), h in bf16 ----------------

__global__ __launch_bounds__(128) void pool_kernel(const unsigned short* __restrict__ h,
                                                   const int* __restrict__ batch,
                                                   float* __restrict__ pooled) {
  int j = threadIdx.x;
  int n0 = blockIdx.x * 256;
  int nend = n0 + 256;
  if (nend > N_NODES) nend = N_NODES;
  int cur = batch[n0];
  float acc = 0.f;
  for (int n = n0; n < nend; ++n) {
    int b = batch[n];
    if (b != cur) {
      atomicAdd(&pooled[cur * HID + j], acc);
      acc = 0.f;
      cur = b;
    }
    acc += bf2f(h[(size_t)n * HID + j]);
  }
  atomicAdd(&pooled[cur * HID + j], acc);
}

// ---------------- final: out[g] = pooled[g] . ffn_w + ffn_b ----------------

__global__ __launch_bounds__(128) void final_kernel(const float* __restrict__ pooled,
                                                    const float* __restrict__ fw,
                                                    const float* __restrict__ fb,
                                                    float* __restrict__ out) {
  int g = blockIdx.x;
  int j = threadIdx.x;
  float v = pooled[g * HID + j] * fw[j];
#pragma unroll
  for (int off = 32; off > 0; off >>= 1) v += __shfl_down(v, off, 64);
  __shared__ float tmp[2];
  if ((j & 63) == 0) tmp[j >> 6] = v;
  __syncthreads();
  if (j == 0) out[g] = tmp[0] + tmp[1] + fb[0];
}

// ---------------- launch ----------------

extern "C" void kernel_launch(void* const* d_in, const int* in_sizes, int n_in,
                              void* d_out, int out_size, void* d_ws, size_t ws_size,
                              hipStream_t stream) {
  const float* x = (const float*)d_in[0];
  const int* edge_index = (const int*)d_in[1];
  const float* edge_attr = (const float*)d_in[2];
  const int* batch = (const int*)d_in[3];
  const float* init_w = (const float*)d_in[4];
  const float* init_b = (const float*)d_in[5];
  const float* edge_w = (const float*)d_in[6];
  const float* edge_b = (const float*)d_in[7];
  const float* mlp_w1 = (const float*)d_in[8];
  const float* mlp_b1 = (const float*)d_in[9];
  const float* mlp_w2 = (const float*)d_in[10];
  const float* mlp_b2 = (const float*)d_in[11];
  const float* ffn_w = (const float*)d_in[12];
  const float* ffn_b = (const float*)d_in[13];

  const int* srcp = edge_index;
  const int* dstp = edge_index + N_EDGES;

  char* ws = (char*)d_ws;
  auto alloc = [&](size_t bytes) {
    char* p = ws;
    ws += (bytes + 255) & ~(size_t)255;
    return p;
  };
  unsigned short* h_bf = (unsigned short*)alloc((size_t)N_NODES * HID * 2);
  unsigned short* h0_bf = (unsigned short*)alloc((size_t)N_NODES * HID * 2);
  unsigned short* z_bf = (unsigned short*)alloc((size_t)N_NODES * HID * 2);
  unsigned short* wfrag = (unsigned short*)alloc((size_t)8 * 16384 * 2);
  int* row_ptr = (int*)alloc((size_t)(N_NODES + 1) * 4);
  int* cursor = (int*)alloc((size_t)N_NODES * 4);
  int* counts = (int*)alloc((size_t)N_NODES * 4);
  int* bsums = (int*)alloc((size_t)SCAN_BLOCKS * 4);
  int* boff = (int*)alloc((size_t)SCAN_BLOCKS * 4);
  int* src_perm = (int*)alloc((size_t)N_EDGES * 4);
  float* ea_perm = (float*)alloc((size_t)N_EDGES * F_EDGE * 4);
  float* pooled = (float*)alloc((size_t)N_GRAPHS * HID * 4);

  hipMemsetAsync(counts, 0, (size_t)N_NODES * 4, stream);
  hipMemsetAsync(pooled, 0, (size_t)N_GRAPHS * HID * 4, stream);

  hist_kernel<<<(N_EDGES + 255) / 256, 256, 0, stream>>>(dstp, counts);
  scan_sum_kernel<<<SCAN_BLOCKS, 256, 0, stream>>>(counts, bsums);
  scan_mid_kernel<<<1, 256, 0, stream>>>(bsums, boff, row_ptr);
  scan_write_kernel<<<SCAN_BLOCKS, 256, 0, stream>>>(counts, boff, row_ptr, cursor);
  scatter_kernel<<<(N_EDGES + 255) / 256, 256, 0, stream>>>(srcp, dstp, edge_attr,
                                                            cursor, src_perm, ea_perm);
  repack_w<<<512, 256, 0, stream>>>(mlp_w1, mlp_w2, wfrag);

  init_kernel<<<N_NODES, 128, 0, stream>>>(x, init_w, init_b, h_bf, h0_bf);

  for (int d = 0; d < DEPTH; ++d) {
    agg_kernel<<<(N_NODES + NODES_PER_BLOCK - 1) / NODES_PER_BLOCK, 64, 0, stream>>>(
        h_bf, src_perm, ea_perm, row_ptr, edge_w + (size_t)d * F_EDGE * HID,
        edge_b + (size_t)d * HID, z_bf);
    fused_mlp<<<512, 256, 0, stream>>>(z_bf, wfrag + (size_t)(2 * d) * 16384,
                                       wfrag + (size_t)(2 * d + 1) * 16384,
                                       mlp_b1 + (size_t)d * HID, mlp_b2 + (size_t)d * HID,
                                       h0_bf, h_bf);
  }

  pool_kernel<<<(N_NODES + 255) / 256, 128, 0, stream>>>(h_bf, batch, pooled);
  final_kernel<<<N_GRAPHS, 128, 0, stream>>>(pooled, ffn_w, ffn_b, (float*)d_out);
}